// Round 16
// baseline (144.992 us; speedup 1.0000x reference)
//
#include <hip/hip_runtime.h>
#include <math.h>

// ---------------------------------------------------------------------------
// B=16, N=1024, C=256, SIZE=(512,640), STRIDE=8 -> H0=64, W0=80, P_TOK=5120
// NHEAD=8, NLVL=4, NPTS=4, HD=32, NUM_CLASSES=7
// pyramid: (64,80)(32,40)(16,20)(8,10); S_total=6800
// Identities: pool2x2 linear => pyramid built AFTER projection (h_t read once/
//   twice); W_o folded into W_p1 bottom half (q_local GEMM eliminated).
// r16: gemm_f32a reshaped M64xN128, acc[2][4]=32 AGPR. Mechanism: m69 reg
//   quantization (waves/SIMD halve at 64/128/256 total regs). Old kernel was
//   72 VGPR + 64 AGPR = 136 -> capped 2 waves/SIMD (the stuck 24.5% occupancy
//   across r11/r13/r15). New budget ~100 -> 4 waves/SIMD -> 2x TLP.
// ---------------------------------------------------------------------------

namespace {

constexpr int kB = 16;
constexpr int kN = 1024;
constexpr int kC = 256;
constexpr int kNCLS = 7;
constexpr int kSTOT = 6800;

typedef __attribute__((ext_vector_type(8))) short short8;
typedef __attribute__((ext_vector_type(4))) float f32x4;

__device__ inline ushort f2bf(float f) {
  union { float f; unsigned u; } v; v.f = f;
  unsigned r = (v.u + 0x7fffu + ((v.u >> 16) & 1u)) >> 16;
  return (ushort)r;
}
__device__ inline float bf2f(ushort h) {
  union { unsigned u; float f; } v; v.u = ((unsigned)h) << 16;
  return v.f;
}

__device__ inline void gload16(const ushort* g, ushort* l) {
  __builtin_amdgcn_global_load_lds(
      (const __attribute__((address_space(1))) void*)g,
      (__attribute__((address_space(3))) void*)l, 16, 0, 0);
}

// ---------------- q_t cast ---------------------------------------------------
__global__ void cast_f2b_kernel(const float* __restrict__ in, ushort* __restrict__ out, int n4) {
  int i = blockIdx.x * 256 + threadIdx.x;
  if (i >= n4) return;
  float4 v = ((const float4*)in)[i];
  ((ushort4*)out)[i] = make_ushort4(f2bf(v.x), f2bf(v.y), f2bf(v.z), f2bf(v.w));
}

// ---------------- fused pyramid: one 8x8 L0 patch -> L1+L2+L3 ---------------
__global__ void pool_all_kernel(ushort* __restrict__ val) {
  int blk = blockIdx.x;  // 1280 = 16*8*10
  int X = blk % 10;
  int t2 = blk / 10;
  int Y = t2 % 8;
  int b = t2 / 8;
  int c = threadIdx.x;
  const ushort* base = val + (((size_t)b * kSTOT + (Y * 8) * 80 + X * 8) << 8) + c;

  float l1[16];
#pragma unroll
  for (int i = 0; i < 16; ++i) {
    int iy = i >> 2, ix = i & 3;
    const ushort* p = base + (((iy * 2) * 80 + ix * 2) << 8);
    l1[i] = 0.25f * (bf2f(p[0]) + bf2f(p[256]) + bf2f(p[80 * 256]) + bf2f(p[80 * 256 + 256]));
  }
#pragma unroll
  for (int i = 0; i < 16; ++i) {
    int iy = i >> 2, ix = i & 3;
    val[(((size_t)b * kSTOT + 5120 + (Y * 4 + iy) * 40 + X * 4 + ix) << 8) + c] = f2bf(l1[i]);
  }
  float l2[4];
#pragma unroll
  for (int j = 0; j < 4; ++j) {
    int jy = j >> 1, jx = j & 1;
    l2[j] = 0.25f * (l1[(2 * jy) * 4 + 2 * jx] + l1[(2 * jy) * 4 + 2 * jx + 1] +
                     l1[(2 * jy + 1) * 4 + 2 * jx] + l1[(2 * jy + 1) * 4 + 2 * jx + 1]);
    val[(((size_t)b * kSTOT + 6400 + (Y * 2 + jy) * 20 + X * 2 + jx) << 8) + c] = f2bf(l2[j]);
  }
  float l3 = 0.25f * (l2[0] + l2[1] + l2[2] + l2[3]);
  val[(((size_t)b * kSTOT + 6720 + Y * 10 + X) << 8) + c] = f2bf(l3);
}

// ---------------- all weight transposes in one launch -----------------------
__global__ void wtrans_all_kernel(const float* __restrict__ s0, const float* __restrict__ s1,
                                  const float* __restrict__ s2, const float* __restrict__ s3,
                                  const float* __restrict__ s4,
                                  ushort* __restrict__ d0, ushort* __restrict__ d1,
                                  ushort* __restrict__ d2, ushort* __restrict__ d3,
                                  ushort* __restrict__ d4) {
  __shared__ float t[32][33];
  const float* W; ushort* Wt; int K, N;
  switch (blockIdx.z) {
    case 0: W = s0; Wt = d0; K = 256; N = 256; break;
    case 1: W = s1; Wt = d1; K = 256; N = 256; break;
    case 2: W = s2; Wt = d2; K = 256; N = 128; break;
    case 3: W = s3; Wt = d3; K = 256; N = 256; break;
    default: W = s4; Wt = d4; K = 512; N = 256; break;
  }
  int nx = blockIdx.x << 5, ky = blockIdx.y << 5;
  if (nx >= N || ky >= K) return;
  int lx = threadIdx.x & 31, ly = threadIdx.x >> 5;
#pragma unroll
  for (int i = 0; i < 32; i += 8)
    t[ly + i][lx] = W[(size_t)(ky + ly + i) * N + nx + lx];
  __syncthreads();
#pragma unroll
  for (int i = 0; i < 32; i += 8)
    Wt[(size_t)(nx + ly + i) * K + ky + lx] = f2bf(t[lx][ly + i]);
}

// ---------------- weight fold: Wt_p1c = [Wp1t^T | (W_o@Wp1b)^T], bias' ------
__global__ void wcomb_kernel(const float* __restrict__ W_o, const float* __restrict__ W_p1,
                             const float* __restrict__ b_o, const float* __restrict__ b_p1,
                             const ushort* __restrict__ Wt_p1,
                             ushort* __restrict__ Wt_p1c, float* __restrict__ bp1c) {
  __shared__ float wcol[256];
  __shared__ float wsum[4];
  int h = blockIdx.x;
  int in = threadIdx.x;
  wcol[in] = W_p1[(size_t)(256 + in) * 256 + h];
  __syncthreads();
  float s = 0.f;
  const float* wo = W_o + (size_t)in * 256;
#pragma unroll 4
  for (int out = 0; out < 256; ++out) s = fmaf(wo[out], wcol[out], s);
  Wt_p1c[(size_t)h * 512 + 256 + in] = f2bf(s);
  Wt_p1c[(size_t)h * 512 + in] = Wt_p1[(size_t)h * 512 + in];
  float part = b_o[in] * wcol[in];
#pragma unroll
  for (int m = 32; m > 0; m >>= 1) part += __shfl_xor(part, m);
  if ((in & 63) == 0) wsum[in >> 6] = part;
  __syncthreads();
  if (in == 0) bp1c[h] = b_p1[h] + wsum[0] + wsum[1] + wsum[2] + wsum[3];
}

// ---------------- bf16 MFMA GEMM, 128x128 tile (small-M GEMMs) --------------
template <int KTOT, bool SPLITK, int OMODE, bool RELU>
__global__ __launch_bounds__(256) void gemm_bf16_kernel(
    const ushort* __restrict__ A, const ushort* __restrict__ A2,
    const ushort* __restrict__ Wt, const float* __restrict__ bias,
    const float* __restrict__ bias2, void* __restrict__ Cout,
    void* __restrict__ Cout2, int ldc) {
  __shared__ ushort Asm[2][128 * 32];
  __shared__ ushort Bsm[2][128 * 32];
  const int tid = threadIdx.x;
  const int w = tid >> 6, l = tid & 63;
  const int bm = blockIdx.y << 7, bn = blockIdx.x << 7;
  const int wm = w >> 1, wn = w & 1;

  const int c0 = w * 2, c1 = w * 2 + 1;
  const int G0 = c0 * 64 + l, G1 = c1 * 64 + l;
  const int r0 = G0 >> 2, g0 = G0 & 3;
  const int r1 = G1 >> 2, g1 = G1 & 3;
  const int sz0 = (g0 ^ ((r0 >> 1) & 3)) << 3;
  const int sz1 = (g1 ^ ((r1 >> 1) & 3)) << 3;
  const int ak = SPLITK ? 256 : KTOT;
  const ushort* sA0 = A + (size_t)(bm + r0) * ak + sz0;
  const ushort* sA1 = A + (size_t)(bm + r1) * ak + sz1;
  const ushort* sA0b = SPLITK ? A2 + (size_t)(bm + r0) * 256 + sz0 : nullptr;
  const ushort* sA1b = SPLITK ? A2 + (size_t)(bm + r1) * 256 + sz1 : nullptr;
  const ushort* sB0 = Wt + (size_t)(bn + r0) * KTOT + sz0;
  const ushort* sB1 = Wt + (size_t)(bn + r1) * KTOT + sz1;

  const int e = l >> 4, rl = l & 15;
  int aoff[4], boff[4];
#pragma unroll
  for (int i = 0; i < 4; ++i) {
    int r = wm * 64 + i * 16 + rl;
    aoff[i] = r * 32 + ((e ^ ((r >> 1) & 3)) << 3);
    int rb = wn * 64 + i * 16 + rl;
    boff[i] = rb * 32 + ((e ^ ((rb >> 1) & 3)) << 3);
  }

  f32x4 acc[4][4];
#pragma unroll
  for (int i = 0; i < 4; ++i)
#pragma unroll
    for (int j = 0; j < 4; ++j) acc[i][j] = (f32x4){0.f, 0.f, 0.f, 0.f};

  auto stage = [&](int buf, int k0) {
    const ushort *a0, *a1;
    if (SPLITK && k0 >= 256) {
      a0 = sA0b + (k0 - 256);
      a1 = sA1b + (k0 - 256);
    } else {
      a0 = sA0 + k0;
      a1 = sA1 + k0;
    }
    gload16(a0, &Asm[buf][c0 * 512]);
    gload16(a1, &Asm[buf][c1 * 512]);
    gload16(sB0 + k0, &Bsm[buf][c0 * 512]);
    gload16(sB1 + k0, &Bsm[buf][c1 * 512]);
  };

  constexpr int nt = KTOT / 32;
  stage(0, 0);
  __syncthreads();
  for (int t = 0; t < nt; ++t) {
    const int cur = t & 1;
    if (t + 1 < nt) stage(cur ^ 1, (t + 1) * 32);
    short8 af[4], bfr[4];
#pragma unroll
    for (int i = 0; i < 4; ++i) af[i] = *(const short8*)&Asm[cur][aoff[i]];
#pragma unroll
    for (int j = 0; j < 4; ++j) bfr[j] = *(const short8*)&Bsm[cur][boff[j]];
#pragma unroll
    for (int i = 0; i < 4; ++i)
#pragma unroll
      for (int j = 0; j < 4; ++j)
        acc[i][j] = __builtin_amdgcn_mfma_f32_16x16x32_bf16(bfr[j], af[i], acc[i][j], 0, 0, 0);
    __syncthreads();
  }

  // epilogue (swapped layout): reg r = channel ch+r, lane&15 = spatial row
#pragma unroll
  for (int j = 0; j < 4; ++j) {
    int ch = bn + wn * 64 + j * 16 + e * 4;
    float4 b4;
    if (OMODE == 2)
      b4 = (ch < 256) ? *(const float4*)(bias + ch) : *(const float4*)(bias2 + ch - 256);
    else
      b4 = *(const float4*)(bias + ch);
    float bv[4] = {b4.x, b4.y, b4.z, b4.w};
#pragma unroll
    for (int i = 0; i < 4; ++i) {
      int sp = bm + wm * 64 + i * 16 + rl;
      float v[4];
#pragma unroll
      for (int r = 0; r < 4; ++r) {
        v[r] = acc[i][j][r] + bv[r];
        if (RELU) v[r] = fmaxf(v[r], 0.f);
      }
      if (OMODE == 0) {
        *(float4*)&((float*)Cout)[(size_t)sp * ldc + ch] = make_float4(v[0], v[1], v[2], v[3]);
      } else if (OMODE == 1) {
        *(ushort4*)&((ushort*)Cout)[(size_t)sp * ldc + ch] =
            make_ushort4(f2bf(v[0]), f2bf(v[1]), f2bf(v[2]), f2bf(v[3]));
      } else {
        if (ch < 256)
          *(float4*)&((float*)Cout)[(size_t)sp * 256 + ch] = make_float4(v[0], v[1], v[2], v[3]);
        else
          *(float4*)&((float*)Cout2)[(size_t)sp * 128 + (ch - 256)] =
              make_float4(v[0], v[1], v[2], v[3]);
      }
    }
  }
}

// ---------------- fp32-A GEMM: value_L0 = h_t @ W_v + b_v -------------------
// M64 x N128 tile, 4 waves (each 32r x 64c), acc[2][4] = 32 AGPR.
// Register budget ~100 total (< the 128-reg m69 cliff) -> 4 waves/SIMD,
// 2x the TLP of the old 136-reg kernel that was hard-capped at 2 waves/SIMD.
// A read 2x across the two N-blocks (h_t 84MB is L3-resident so re-read is
// Infinity-Cache-absorbed). r12 dbuf loop shape (proven best of r11/r13/r15).
__global__ __launch_bounds__(256) void gemm_f32a_kernel(
    const float* __restrict__ A, const ushort* __restrict__ Wt,
    const float* __restrict__ bias, ushort* __restrict__ Cout) {
  __shared__ ushort Asm[2][64 * 32];   // 4 KB each
  __shared__ ushort Bsm[2][128 * 32];  // 8 KB each
  const int tid = threadIdx.x;
  const int w = tid >> 6, l = tid & 63;
  const int by = blockIdx.y;           // 1280 M-tiles of 64 rows
  const int bn = blockIdx.x << 7;      // 0 / 128
  const int bm = by << 6;
  const int wm = w >> 1, wn = w & 1;   // wave: rows wm*32.., cols wn*64..

  // A staging: thread -> row ar = tid>>2, k-octet aq = tid&3 (8 floats)
  const int ar = tid >> 2, aq = tid & 3;
  const float* aSrc = A + (size_t)(bm + ar) * 256 + aq * 8;
  const int adst = ar * 32 + ((aq ^ ((ar >> 1) & 3)) << 3);

  // B staging: 8 chunks of 1KB, wave w -> chunks 2w, 2w+1 (gload16)
  const int c0 = w * 2, c1 = w * 2 + 1;
  const int G0 = c0 * 64 + l, G1 = c1 * 64 + l;
  const int r0 = G0 >> 2, g0 = G0 & 3;
  const int r1 = G1 >> 2, g1 = G1 & 3;
  const ushort* sB0 = Wt + (size_t)(bn + r0) * 256 + ((g0 ^ ((r0 >> 1) & 3)) << 3);
  const ushort* sB1 = Wt + (size_t)(bn + r1) * 256 + ((g1 ^ ((r1 >> 1) & 3)) << 3);

  const int e = l >> 4, rl = l & 15;
  int aoff[2], boff[4];
#pragma unroll
  for (int i = 0; i < 2; ++i) {
    int r = wm * 32 + i * 16 + rl;
    aoff[i] = r * 32 + ((e ^ ((r >> 1) & 3)) << 3);
  }
#pragma unroll
  for (int j = 0; j < 4; ++j) {
    int rb = wn * 64 + j * 16 + rl;
    boff[j] = rb * 32 + ((e ^ ((rb >> 1) & 3)) << 3);
  }

  f32x4 acc[2][4];
#pragma unroll
  for (int i = 0; i < 2; ++i)
#pragma unroll
    for (int j = 0; j < 4; ++j) acc[i][j] = (f32x4){0.f, 0.f, 0.f, 0.f};

  float4 av0, av1;
  auto loadA = [&](int k0) {
    av0 = *(const float4*)(aSrc + k0);
    av1 = *(const float4*)(aSrc + k0 + 4);
  };
  auto writeA = [&](int buf) {
    *(short8*)&Asm[buf][adst] =
        (short8){(short)f2bf(av0.x), (short)f2bf(av0.y), (short)f2bf(av0.z), (short)f2bf(av0.w),
                 (short)f2bf(av1.x), (short)f2bf(av1.y), (short)f2bf(av1.z), (short)f2bf(av1.w)};
  };
  auto stageB = [&](int buf, int k0) {
    gload16(sB0 + k0, &Bsm[buf][c0 * 512]);
    gload16(sB1 + k0, &Bsm[buf][c1 * 512]);
  };

  loadA(0);
  stageB(0, 0);
  writeA(0);
  __syncthreads();
  for (int t = 0; t < 8; ++t) {
    const int cur = t & 1;
    if (t < 7) {
      loadA((t + 1) * 32);   // issue next A loads early (hide under MFMA)
      stageB(cur ^ 1, (t + 1) * 32);
    }
    short8 af[2], bfr[4];
#pragma unroll
    for (int i = 0; i < 2; ++i) af[i] = *(const short8*)&Asm[cur][aoff[i]];
#pragma unroll
    for (int j = 0; j < 4; ++j) bfr[j] = *(const short8*)&Bsm[cur][boff[j]];
#pragma unroll
    for (int i = 0; i < 2; ++i)
#pragma unroll
      for (int j = 0; j < 4; ++j)
        acc[i][j] = __builtin_amdgcn_mfma_f32_16x16x32_bf16(bfr[j], af[i], acc[i][j], 0, 0, 0);
    if (t < 7) writeA(cur ^ 1);  // cvt + ds_write after compute
    __syncthreads();
  }

  // epilogue (swapped layout) into value's 6800-stride L0 region
  const int b = by / 80;               // 5120/64 = 80 tiles per batch
  const int sb = (by - b * 80) << 6;
  ushort* outB = Cout + (((size_t)(b * 6800 + sb)) << 8);
#pragma unroll
  for (int j = 0; j < 4; ++j) {
    int ch = bn + wn * 64 + j * 16 + e * 4;
    float4 b4 = *(const float4*)(bias + ch);
    float bv[4] = {b4.x, b4.y, b4.z, b4.w};
#pragma unroll
    for (int i = 0; i < 2; ++i) {
      int sp = wm * 32 + i * 16 + rl;
      float v[4];
#pragma unroll
      for (int r = 0; r < 4; ++r) v[r] = acc[i][j][r] + bv[r];
      *(ushort4*)&outB[(size_t)sp * 256 + ch] =
          make_ushort4(f2bf(v[0]), f2bf(v[1]), f2bf(v[2]), f2bf(v[3]));
    }
  }
}

// ---------------- deformable sampling, softmax fused ------------------------
__global__ void deform_kernel(
    const ushort* __restrict__ value, const float* __restrict__ off,
    const float* __restrict__ attnl, const float* __restrict__ p_head,
    ushort* __restrict__ samp) {
  int blk = (int)blockIdx.x;
  int sw = (blk & 7) * 256 + (blk >> 3);
  int wvi = (sw << 2) + (threadIdx.x >> 6);
  int l = threadIdx.x & 63;
  int nq = l >> 5;
  int lh = l & 31;
  int h = lh >> 2;
  int pt = wvi * 2 + nq;
  int b = pt >> 10;
  size_t bn = (size_t)pt;

  float ph = (lh < 2) ? p_head[bn * 2 + lh] : 0.f;
  float px = __shfl(ph, (nq << 5) + 0, 64) * (1.0f / 640.0f);
  float py = __shfl(ph, (nq << 5) + 1, 64) * (1.0f / 512.0f);
  px = fminf(fmaxf(px, 0.f), 1.f);
  py = fminf(fmaxf(py, 0.f), 1.f);

  const float4* offp = (const float4*)(off + (bn << 8));
  float4 ofv0 = offp[2 * lh];
  float4 ofv1 = offp[2 * lh + 1];
  float4 atv = ((const float4*)(attnl + (bn << 7)))[lh];

  float m = fmaxf(fmaxf(atv.x, atv.y), fmaxf(atv.z, atv.w));
  m = fmaxf(m, __shfl_xor(m, 1, 64));
  m = fmaxf(m, __shfl_xor(m, 2, 64));
  float e0 = expf(atv.x - m), e1 = expf(atv.y - m);
  float e2 = expf(atv.z - m), e3 = expf(atv.w - m);
  float s = e0 + e1 + e2 + e3;
  s += __shfl_xor(s, 1, 64);
  s += __shfl_xor(s, 2, 64);
  float inv = 1.f / s;
  atv = make_float4(e0 * inv, e1 * inv, e2 * inv, e3 * inv);

  float acc[8];
#pragma unroll
  for (int i = 0; i < 8; ++i) acc[i] = 0.f;
  const ushort* vbb = value + (((size_t)b * kSTOT) << 8) + (lh << 3);

#pragma unroll 1
  for (int lv = 0; lv < 4; ++lv) {
    const int Wl = 80 >> lv, Hl = 64 >> lv;
    const int offL = (lv == 0) ? 0 : (lv == 1) ? 5120 : (lv == 2) ? 6400 : 6720;
    const ushort* vb = vbb + (((size_t)offL) << 8);
    const int src = (nq << 5) + (h << 2) + lv;
    const float fx = px * (float)Wl - 0.5f;
    const float fy = py * (float)Hl - 0.5f;
#pragma unroll
    for (int pp = 0; pp < 4; ++pp) {
      float sx, sy;
      if ((pp >> 1) == 0) {
        sx = (pp & 1) ? ofv0.z : ofv0.x;
        sy = (pp & 1) ? ofv0.w : ofv0.y;
      } else {
        sx = (pp & 1) ? ofv1.z : ofv1.x;
        sy = (pp & 1) ? ofv1.w : ofv1.y;
      }
      float ox = __shfl(sx, src, 64);
      float oy = __shfl(sy, src, 64);
      float sa = pp == 0 ? atv.x : pp == 1 ? atv.y : pp == 2 ? atv.z : atv.w;
      float aw = __shfl(sa, src, 64);

      float xx = fx + ox;
      float yy = fy + oy;
      float x0f = floorf(xx), y0f = floorf(yy);
      float wx = xx - x0f, wy = yy - y0f;
      int x0 = (int)x0f, y0 = (int)y0f;
      float w00 = (1.f - wx) * (1.f - wy) * aw;
      float w01 = wx * (1.f - wy) * aw;
      float w10 = (1.f - wx) * wy * aw;
      float w11 = wx * wy * aw;
      auto corner = [&](int xi, int yi, float wgt) {
        bool valid = (xi >= 0) && (xi < Wl) && (yi >= 0) && (yi < Hl);
        int xc = xi < 0 ? 0 : (xi > Wl - 1 ? Wl - 1 : xi);
        int yc = yi < 0 ? 0 : (yi > Hl - 1 ? Hl - 1 : yi);
        short8 d = *(const short8*)(vb + (((size_t)(yc * Wl + xc)) << 8));
        float wg = valid ? wgt : 0.f;
#pragma unroll
        for (int i = 0; i < 8; ++i) acc[i] = fmaf(wg, bf2f((ushort)d[i]), acc[i]);
      };
      corner(x0, y0, w00);
      corner(x0 + 1, y0, w01);
      corner(x0, y0 + 1, w10);
      corner(x0 + 1, y0 + 1, w11);
    }
  }
  ushort o[8];
#pragma unroll
  for (int i = 0; i < 8; ++i) o[i] = f2bf(acc[i]);
  *(short8*)(samp + (bn << 8) + (lh << 3)) =
      (short8){(short)o[0], (short)o[1], (short)o[2], (short)o[3],
               (short)o[4], (short)o[5], (short)o[6], (short)o[7]};
}

// ---------------- final head: (B*N,256)@(256,7)+b, one wave per row ---------
__global__ void head_kernel(const float* __restrict__ hid, const float* __restrict__ W2,
                            const float* __restrict__ b2, float* __restrict__ outp) {
  int gid = blockIdx.x * 256 + threadIdx.x;
  int wave = gid >> 6;
  int lane = threadIdx.x & 63;
  if (wave >= kB * kN) return;
  const float* hrow = hid + ((size_t)wave << 8);
  float acc[kNCLS];
#pragma unroll
  for (int j = 0; j < kNCLS; ++j) acc[j] = 0.f;
  for (int k = lane; k < kC; k += 64) {
    float hv = hrow[k];
    const float* wr = W2 + k * kNCLS;
#pragma unroll
    for (int j = 0; j < kNCLS; ++j) acc[j] = fmaf(hv, wr[j], acc[j]);
  }
#pragma unroll
  for (int m = 32; m > 0; m >>= 1) {
#pragma unroll
    for (int j = 0; j < kNCLS; ++j) acc[j] += __shfl_xor(acc[j], m);
  }
  float r = 0.f;
#pragma unroll
  for (int j = 0; j < kNCLS; ++j)
    if (lane == j) r = acc[j] + b2[j];
  if (lane < kNCLS) outp[(size_t)wave * kNCLS + lane] = r;
}

}  // namespace

extern "C" void kernel_launch(void* const* d_in, const int* in_sizes, int n_in,
                              void* d_out, int out_size, void* d_ws, size_t ws_size,
                              hipStream_t stream) {
  const float* q_t    = (const float*)d_in[0];
  const float* h_t    = (const float*)d_in[1];
  const float* p_head = (const float*)d_in[2];
  const float* W_off  = (const float*)d_in[3];
  const float* b_off  = (const float*)d_in[4];
  const float* W_attn = (const float*)d_in[5];
  const float* b_attn = (const float*)d_in[6];
  const float* W_v    = (const float*)d_in[7];
  const float* b_v    = (const float*)d_in[8];
  const float* W_o    = (const float*)d_in[9];
  const float* b_o    = (const float*)d_in[10];
  const float* W_p1   = (const float*)d_in[11];
  const float* b_p1   = (const float*)d_in[12];
  const float* W_p2   = (const float*)d_in[13];
  const float* b_p2   = (const float*)d_in[14];
  float* out = (float*)d_out;
  char* wsb = (char*)d_ws;

  ushort* value = (ushort*)(wsb + 55705600);     // 55,705,600 (6800-stride)
  ushort* q_bf  = (ushort*)(wsb + 111411200);    //  8,388,608
  float*  offb  = (float*)(wsb + 119799808);     // 16,777,216
  float*  attnl = (float*)(wsb + 136577024);     //  8,388,608 (raw logits)
  ushort* samp  = (ushort*)(wsb + 144965632);    //  8,388,608
  float*  hid   = (float*)(wsb + 161742848);     // 16,777,216
  ushort* wtp   = (ushort*)(wsb + 178520064);
  ushort* Wt_v   = wtp;                 // [256][256]
  ushort* Wt_oa  = wtp + 65536;         // [384][256]
  ushort* Wt_o   = wtp + 163840;        // [256][256]
  ushort* Wt_p1  = wtp + 229376;        // [256][512]
  ushort* Wt_p1c = wtp + 360448;        // [256][512] combined
  float*  bp1c   = (float*)(wtp + 491520);  // [256] fp32

  cast_f2b_kernel<<<4096, 256, 0, stream>>>(q_t, q_bf, kB * kN * 64);

  wtrans_all_kernel<<<dim3(8, 16, 5), 256, 0, stream>>>(
      W_v, W_off, W_attn, W_o, W_p1,
      Wt_v, Wt_oa, Wt_oa + 65536, Wt_o, Wt_p1);

  // fold W_o into W_p1 bottom half (kills the q_local GEMM)
  wcomb_kernel<<<256, 256, 0, stream>>>(W_o, W_p1, b_o, b_p1, Wt_p1, Wt_p1c, bp1c);

  // value_L0 = h_t @ W_v + b_v  (M64xN128, 32-AGPR occupancy form)
  gemm_f32a_kernel<<<dim3(2, 1280), 256, 0, stream>>>(h_t, Wt_v, b_v, value);

  // value pyramid: one fused kernel, in-register cascade per 8x8 patch
  pool_all_kernel<<<1280, 256, 0, stream>>>(value);

  gemm_bf16_kernel<256, false, 2, false><<<dim3(3, 128), 256, 0, stream>>>(
      q_bf, nullptr, Wt_oa, b_off, b_attn, offb, attnl, 256);

  deform_kernel<<<2048, 256, 0, stream>>>(value, offb, attnl, p_head, samp);

  // hid = relu(q_t@Wp1t + samp@Wc + b')  (split-K, q_local GEMM eliminated)
  gemm_bf16_kernel<512, true, 0, true><<<dim3(2, 128), 256, 0, stream>>>(
      q_bf, samp, Wt_p1c, bp1c, nullptr, hid, nullptr, 256);

  head_kernel<<<4096, 256, 0, stream>>>(hid, W_p2, b_p2, out);
}

// Round 17
// 144.979 us; speedup vs baseline: 1.0001x; 1.0001x over previous
//
#include <hip/hip_runtime.h>
#include <math.h>

// ---------------------------------------------------------------------------
// B=16, N=1024, C=256, SIZE=(512,640), STRIDE=8 -> H0=64, W0=80, P_TOK=5120
// NHEAD=8, NLVL=4, NPTS=4, HD=32, NUM_CLASSES=7
// pyramid: (64,80)(32,40)(16,20)(8,10); S_total=6800
// Identities: pool2x2 linear => pyramid built AFTER projection; W_o folded
//   into W_p1 bottom half (q_local GEMM eliminated).
// r17: deform block->XCD swizzle changed from batch-SPREADING to batch-OWNING:
//   XCD x (blk&7, assuming %8 round-robin) processes batch 2x then 2x+1; one
//   batch's value slice = 3.5MB fits the 4MB per-XCD L2 -> gathers L2-hit.
// gemm_f32a frozen at ~61us: tile-up(r11)/vmcnt(r13)/1buf(r15)/reg-down(r16)
//   all falsified; occupancy & registers proven non-binding.
// ---------------------------------------------------------------------------

namespace {

constexpr int kB = 16;
constexpr int kN = 1024;
constexpr int kC = 256;
constexpr int kNCLS = 7;
constexpr int kSTOT = 6800;

typedef __attribute__((ext_vector_type(8))) short short8;
typedef __attribute__((ext_vector_type(4))) float f32x4;

__device__ inline ushort f2bf(float f) {
  union { float f; unsigned u; } v; v.f = f;
  unsigned r = (v.u + 0x7fffu + ((v.u >> 16) & 1u)) >> 16;
  return (ushort)r;
}
__device__ inline float bf2f(ushort h) {
  union { unsigned u; float f; } v; v.u = ((unsigned)h) << 16;
  return v.f;
}

__device__ inline void gload16(const ushort* g, ushort* l) {
  __builtin_amdgcn_global_load_lds(
      (const __attribute__((address_space(1))) void*)g,
      (__attribute__((address_space(3))) void*)l, 16, 0, 0);
}

// ---------------- q_t cast ---------------------------------------------------
__global__ void cast_f2b_kernel(const float* __restrict__ in, ushort* __restrict__ out, int n4) {
  int i = blockIdx.x * 256 + threadIdx.x;
  if (i >= n4) return;
  float4 v = ((const float4*)in)[i];
  ((ushort4*)out)[i] = make_ushort4(f2bf(v.x), f2bf(v.y), f2bf(v.z), f2bf(v.w));
}

// ---------------- fused pyramid: one 8x8 L0 patch -> L1+L2+L3 ---------------
__global__ void pool_all_kernel(ushort* __restrict__ val) {
  int blk = blockIdx.x;  // 1280 = 16*8*10
  int X = blk % 10;
  int t2 = blk / 10;
  int Y = t2 % 8;
  int b = t2 / 8;
  int c = threadIdx.x;
  const ushort* base = val + (((size_t)b * kSTOT + (Y * 8) * 80 + X * 8) << 8) + c;

  float l1[16];
#pragma unroll
  for (int i = 0; i < 16; ++i) {
    int iy = i >> 2, ix = i & 3;
    const ushort* p = base + (((iy * 2) * 80 + ix * 2) << 8);
    l1[i] = 0.25f * (bf2f(p[0]) + bf2f(p[256]) + bf2f(p[80 * 256]) + bf2f(p[80 * 256 + 256]));
  }
#pragma unroll
  for (int i = 0; i < 16; ++i) {
    int iy = i >> 2, ix = i & 3;
    val[(((size_t)b * kSTOT + 5120 + (Y * 4 + iy) * 40 + X * 4 + ix) << 8) + c] = f2bf(l1[i]);
  }
  float l2[4];
#pragma unroll
  for (int j = 0; j < 4; ++j) {
    int jy = j >> 1, jx = j & 1;
    l2[j] = 0.25f * (l1[(2 * jy) * 4 + 2 * jx] + l1[(2 * jy) * 4 + 2 * jx + 1] +
                     l1[(2 * jy + 1) * 4 + 2 * jx] + l1[(2 * jy + 1) * 4 + 2 * jx + 1]);
    val[(((size_t)b * kSTOT + 6400 + (Y * 2 + jy) * 20 + X * 2 + jx) << 8) + c] = f2bf(l2[j]);
  }
  float l3 = 0.25f * (l2[0] + l2[1] + l2[2] + l2[3]);
  val[(((size_t)b * kSTOT + 6720 + Y * 10 + X) << 8) + c] = f2bf(l3);
}

// ---------------- weight transposes (W_o dropped — folded away) -------------
__global__ void wtrans_all_kernel(const float* __restrict__ s0, const float* __restrict__ s1,
                                  const float* __restrict__ s2, const float* __restrict__ s3,
                                  ushort* __restrict__ d0, ushort* __restrict__ d1,
                                  ushort* __restrict__ d2, ushort* __restrict__ d3) {
  __shared__ float t[32][33];
  const float* W; ushort* Wt; int K, N;
  switch (blockIdx.z) {
    case 0: W = s0; Wt = d0; K = 256; N = 256; break;
    case 1: W = s1; Wt = d1; K = 256; N = 256; break;
    case 2: W = s2; Wt = d2; K = 256; N = 128; break;
    default: W = s3; Wt = d3; K = 512; N = 256; break;
  }
  int nx = blockIdx.x << 5, ky = blockIdx.y << 5;
  if (nx >= N || ky >= K) return;
  int lx = threadIdx.x & 31, ly = threadIdx.x >> 5;
#pragma unroll
  for (int i = 0; i < 32; i += 8)
    t[ly + i][lx] = W[(size_t)(ky + ly + i) * N + nx + lx];
  __syncthreads();
#pragma unroll
  for (int i = 0; i < 32; i += 8)
    Wt[(size_t)(nx + ly + i) * K + ky + lx] = f2bf(t[lx][ly + i]);
}

// ---------------- weight fold: Wt_p1c = [Wp1t^T | (W_o@Wp1b)^T], bias' ------
__global__ void wcomb_kernel(const float* __restrict__ W_o, const float* __restrict__ W_p1,
                             const float* __restrict__ b_o, const float* __restrict__ b_p1,
                             const ushort* __restrict__ Wt_p1,
                             ushort* __restrict__ Wt_p1c, float* __restrict__ bp1c) {
  __shared__ float wcol[256];
  __shared__ float wsum[4];
  int h = blockIdx.x;
  int in = threadIdx.x;
  wcol[in] = W_p1[(size_t)(256 + in) * 256 + h];
  __syncthreads();
  float s = 0.f;
  const float* wo = W_o + (size_t)in * 256;
#pragma unroll 4
  for (int out = 0; out < 256; ++out) s = fmaf(wo[out], wcol[out], s);
  Wt_p1c[(size_t)h * 512 + 256 + in] = f2bf(s);
  Wt_p1c[(size_t)h * 512 + in] = Wt_p1[(size_t)h * 512 + in];
  float part = b_o[in] * wcol[in];
#pragma unroll
  for (int m = 32; m > 0; m >>= 1) part += __shfl_xor(part, m);
  if ((in & 63) == 0) wsum[in >> 6] = part;
  __syncthreads();
  if (in == 0) bp1c[h] = b_p1[h] + wsum[0] + wsum[1] + wsum[2] + wsum[3];
}

// ---------------- bf16 MFMA GEMM, 128x128 tile (small-M GEMMs) --------------
template <int KTOT, bool SPLITK, int OMODE, bool RELU>
__global__ __launch_bounds__(256) void gemm_bf16_kernel(
    const ushort* __restrict__ A, const ushort* __restrict__ A2,
    const ushort* __restrict__ Wt, const float* __restrict__ bias,
    const float* __restrict__ bias2, void* __restrict__ Cout,
    void* __restrict__ Cout2, int ldc) {
  __shared__ ushort Asm[2][128 * 32];
  __shared__ ushort Bsm[2][128 * 32];
  const int tid = threadIdx.x;
  const int w = tid >> 6, l = tid & 63;
  const int bm = blockIdx.y << 7, bn = blockIdx.x << 7;
  const int wm = w >> 1, wn = w & 1;

  const int c0 = w * 2, c1 = w * 2 + 1;
  const int G0 = c0 * 64 + l, G1 = c1 * 64 + l;
  const int r0 = G0 >> 2, g0 = G0 & 3;
  const int r1 = G1 >> 2, g1 = G1 & 3;
  const int sz0 = (g0 ^ ((r0 >> 1) & 3)) << 3;
  const int sz1 = (g1 ^ ((r1 >> 1) & 3)) << 3;
  const int ak = SPLITK ? 256 : KTOT;
  const ushort* sA0 = A + (size_t)(bm + r0) * ak + sz0;
  const ushort* sA1 = A + (size_t)(bm + r1) * ak + sz1;
  const ushort* sA0b = SPLITK ? A2 + (size_t)(bm + r0) * 256 + sz0 : nullptr;
  const ushort* sA1b = SPLITK ? A2 + (size_t)(bm + r1) * 256 + sz1 : nullptr;
  const ushort* sB0 = Wt + (size_t)(bn + r0) * KTOT + sz0;
  const ushort* sB1 = Wt + (size_t)(bn + r1) * KTOT + sz1;

  const int e = l >> 4, rl = l & 15;
  int aoff[4], boff[4];
#pragma unroll
  for (int i = 0; i < 4; ++i) {
    int r = wm * 64 + i * 16 + rl;
    aoff[i] = r * 32 + ((e ^ ((r >> 1) & 3)) << 3);
    int rb = wn * 64 + i * 16 + rl;
    boff[i] = rb * 32 + ((e ^ ((rb >> 1) & 3)) << 3);
  }

  f32x4 acc[4][4];
#pragma unroll
  for (int i = 0; i < 4; ++i)
#pragma unroll
    for (int j = 0; j < 4; ++j) acc[i][j] = (f32x4){0.f, 0.f, 0.f, 0.f};

  auto stage = [&](int buf, int k0) {
    const ushort *a0, *a1;
    if (SPLITK && k0 >= 256) {
      a0 = sA0b + (k0 - 256);
      a1 = sA1b + (k0 - 256);
    } else {
      a0 = sA0 + k0;
      a1 = sA1 + k0;
    }
    gload16(a0, &Asm[buf][c0 * 512]);
    gload16(a1, &Asm[buf][c1 * 512]);
    gload16(sB0 + k0, &Bsm[buf][c0 * 512]);
    gload16(sB1 + k0, &Bsm[buf][c1 * 512]);
  };

  constexpr int nt = KTOT / 32;
  stage(0, 0);
  __syncthreads();
  for (int t = 0; t < nt; ++t) {
    const int cur = t & 1;
    if (t + 1 < nt) stage(cur ^ 1, (t + 1) * 32);
    short8 af[4], bfr[4];
#pragma unroll
    for (int i = 0; i < 4; ++i) af[i] = *(const short8*)&Asm[cur][aoff[i]];
#pragma unroll
    for (int j = 0; j < 4; ++j) bfr[j] = *(const short8*)&Bsm[cur][boff[j]];
#pragma unroll
    for (int i = 0; i < 4; ++i)
#pragma unroll
      for (int j = 0; j < 4; ++j)
        acc[i][j] = __builtin_amdgcn_mfma_f32_16x16x32_bf16(bfr[j], af[i], acc[i][j], 0, 0, 0);
    __syncthreads();
  }

  // epilogue (swapped layout): reg r = channel ch+r, lane&15 = spatial row
#pragma unroll
  for (int j = 0; j < 4; ++j) {
    int ch = bn + wn * 64 + j * 16 + e * 4;
    float4 b4;
    if (OMODE == 2)
      b4 = (ch < 256) ? *(const float4*)(bias + ch) : *(const float4*)(bias2 + ch - 256);
    else
      b4 = *(const float4*)(bias + ch);
    float bv[4] = {b4.x, b4.y, b4.z, b4.w};
#pragma unroll
    for (int i = 0; i < 4; ++i) {
      int sp = bm + wm * 64 + i * 16 + rl;
      float v[4];
#pragma unroll
      for (int r = 0; r < 4; ++r) {
        v[r] = acc[i][j][r] + bv[r];
        if (RELU) v[r] = fmaxf(v[r], 0.f);
      }
      if (OMODE == 0) {
        *(float4*)&((float*)Cout)[(size_t)sp * ldc + ch] = make_float4(v[0], v[1], v[2], v[3]);
      } else if (OMODE == 1) {
        *(ushort4*)&((ushort*)Cout)[(size_t)sp * ldc + ch] =
            make_ushort4(f2bf(v[0]), f2bf(v[1]), f2bf(v[2]), f2bf(v[3]));
      } else {
        if (ch < 256)
          *(float4*)&((float*)Cout)[(size_t)sp * 256 + ch] = make_float4(v[0], v[1], v[2], v[3]);
        else
          *(float4*)&((float*)Cout2)[(size_t)sp * 128 + (ch - 256)] =
              make_float4(v[0], v[1], v[2], v[3]);
      }
    }
  }
}

// ---------------- fp32-A GEMM: value_L0 = h_t @ W_v + b_v (frozen r16) ------
__global__ __launch_bounds__(256) void gemm_f32a_kernel(
    const float* __restrict__ A, const ushort* __restrict__ Wt,
    const float* __restrict__ bias, ushort* __restrict__ Cout) {
  __shared__ ushort Asm[2][64 * 32];
  __shared__ ushort Bsm[2][128 * 32];
  const int tid = threadIdx.x;
  const int w = tid >> 6, l = tid & 63;
  const int by = blockIdx.y;
  const int bn = blockIdx.x << 7;
  const int bm = by << 6;
  const int wm = w >> 1, wn = w & 1;

  const int ar = tid >> 2, aq = tid & 3;
  const float* aSrc = A + (size_t)(bm + ar) * 256 + aq * 8;
  const int adst = ar * 32 + ((aq ^ ((ar >> 1) & 3)) << 3);

  const int c0 = w * 2, c1 = w * 2 + 1;
  const int G0 = c0 * 64 + l, G1 = c1 * 64 + l;
  const int r0 = G0 >> 2, g0 = G0 & 3;
  const int r1 = G1 >> 2, g1 = G1 & 3;
  const ushort* sB0 = Wt + (size_t)(bn + r0) * 256 + ((g0 ^ ((r0 >> 1) & 3)) << 3);
  const ushort* sB1 = Wt + (size_t)(bn + r1) * 256 + ((g1 ^ ((r1 >> 1) & 3)) << 3);

  const int e = l >> 4, rl = l & 15;
  int aoff[2], boff[4];
#pragma unroll
  for (int i = 0; i < 2; ++i) {
    int r = wm * 32 + i * 16 + rl;
    aoff[i] = r * 32 + ((e ^ ((r >> 1) & 3)) << 3);
  }
#pragma unroll
  for (int j = 0; j < 4; ++j) {
    int rb = wn * 64 + j * 16 + rl;
    boff[j] = rb * 32 + ((e ^ ((rb >> 1) & 3)) << 3);
  }

  f32x4 acc[2][4];
#pragma unroll
  for (int i = 0; i < 2; ++i)
#pragma unroll
    for (int j = 0; j < 4; ++j) acc[i][j] = (f32x4){0.f, 0.f, 0.f, 0.f};

  float4 av0, av1;
  auto loadA = [&](int k0) {
    av0 = *(const float4*)(aSrc + k0);
    av1 = *(const float4*)(aSrc + k0 + 4);
  };
  auto writeA = [&](int buf) {
    *(short8*)&Asm[buf][adst] =
        (short8){(short)f2bf(av0.x), (short)f2bf(av0.y), (short)f2bf(av0.z), (short)f2bf(av0.w),
                 (short)f2bf(av1.x), (short)f2bf(av1.y), (short)f2bf(av1.z), (short)f2bf(av1.w)};
  };
  auto stageB = [&](int buf, int k0) {
    gload16(sB0 + k0, &Bsm[buf][c0 * 512]);
    gload16(sB1 + k0, &Bsm[buf][c1 * 512]);
  };

  loadA(0);
  stageB(0, 0);
  writeA(0);
  __syncthreads();
  for (int t = 0; t < 8; ++t) {
    const int cur = t & 1;
    if (t < 7) {
      loadA((t + 1) * 32);
      stageB(cur ^ 1, (t + 1) * 32);
    }
    short8 af[2], bfr[4];
#pragma unroll
    for (int i = 0; i < 2; ++i) af[i] = *(const short8*)&Asm[cur][aoff[i]];
#pragma unroll
    for (int j = 0; j < 4; ++j) bfr[j] = *(const short8*)&Bsm[cur][boff[j]];
#pragma unroll
    for (int i = 0; i < 2; ++i)
#pragma unroll
      for (int j = 0; j < 4; ++j)
        acc[i][j] = __builtin_amdgcn_mfma_f32_16x16x32_bf16(bfr[j], af[i], acc[i][j], 0, 0, 0);
    if (t < 7) writeA(cur ^ 1);
    __syncthreads();
  }

  const int b = by / 80;
  const int sb = (by - b * 80) << 6;
  ushort* outB = Cout + (((size_t)(b * 6800 + sb)) << 8);
#pragma unroll
  for (int j = 0; j < 4; ++j) {
    int ch = bn + wn * 64 + j * 16 + e * 4;
    float4 b4 = *(const float4*)(bias + ch);
    float bv[4] = {b4.x, b4.y, b4.z, b4.w};
#pragma unroll
    for (int i = 0; i < 2; ++i) {
      int sp = wm * 32 + i * 16 + rl;
      float v[4];
#pragma unroll
      for (int r = 0; r < 4; ++r) v[r] = acc[i][j][r] + bv[r];
      *(ushort4*)&outB[(size_t)sp * 256 + ch] =
          make_ushort4(f2bf(v[0]), f2bf(v[1]), f2bf(v[2]), f2bf(v[3]));
    }
  }
}

// ---------------- deformable sampling, softmax fused ------------------------
// Batch-owning XCD swizzle: xcd = blk&7 (assumes %8 round-robin block->XCD),
// wvi = xcd*1024 + (blk>>3)*4 + wave  (bijective over [0,8192)).
// XCD x thus gathers only from batches 2x (blocks j<128) then 2x+1 — each
// batch's value slice is 3.5MB < 4MB per-XCD L2 -> gathers become L2 hits
// (537MB total gather traffic was L3-bound before).
__global__ void deform_kernel(
    const ushort* __restrict__ value, const float* __restrict__ off,
    const float* __restrict__ attnl, const float* __restrict__ p_head,
    ushort* __restrict__ samp) {
  int blk = (int)blockIdx.x;            // 2048 blocks
  int xcd = blk & 7;
  int j = blk >> 3;                     // [0,256) per XCD, in launch order
  int wvi = (xcd << 10) + (j << 2) + (threadIdx.x >> 6);
  int l = threadIdx.x & 63;
  int nq = l >> 5;
  int lh = l & 31;
  int h = lh >> 2;
  int pt = wvi * 2 + nq;
  int b = pt >> 10;
  size_t bn = (size_t)pt;

  float ph = (lh < 2) ? p_head[bn * 2 + lh] : 0.f;
  float px = __shfl(ph, (nq << 5) + 0, 64) * (1.0f / 640.0f);
  float py = __shfl(ph, (nq << 5) + 1, 64) * (1.0f / 512.0f);
  px = fminf(fmaxf(px, 0.f), 1.f);
  py = fminf(fmaxf(py, 0.f), 1.f);

  const float4* offp = (const float4*)(off + (bn << 8));
  float4 ofv0 = offp[2 * lh];
  float4 ofv1 = offp[2 * lh + 1];
  float4 atv = ((const float4*)(attnl + (bn << 7)))[lh];

  float m = fmaxf(fmaxf(atv.x, atv.y), fmaxf(atv.z, atv.w));
  m = fmaxf(m, __shfl_xor(m, 1, 64));
  m = fmaxf(m, __shfl_xor(m, 2, 64));
  float e0 = expf(atv.x - m), e1 = expf(atv.y - m);
  float e2 = expf(atv.z - m), e3 = expf(atv.w - m);
  float s = e0 + e1 + e2 + e3;
  s += __shfl_xor(s, 1, 64);
  s += __shfl_xor(s, 2, 64);
  float inv = 1.f / s;
  atv = make_float4(e0 * inv, e1 * inv, e2 * inv, e3 * inv);

  float acc[8];
#pragma unroll
  for (int i = 0; i < 8; ++i) acc[i] = 0.f;
  const ushort* vbb = value + (((size_t)b * kSTOT) << 8) + (lh << 3);

#pragma unroll 1
  for (int lv = 0; lv < 4; ++lv) {
    const int Wl = 80 >> lv, Hl = 64 >> lv;
    const int offL = (lv == 0) ? 0 : (lv == 1) ? 5120 : (lv == 2) ? 6400 : 6720;
    const ushort* vb = vbb + (((size_t)offL) << 8);
    const int src = (nq << 5) + (h << 2) + lv;
    const float fx = px * (float)Wl - 0.5f;
    const float fy = py * (float)Hl - 0.5f;
#pragma unroll
    for (int pp = 0; pp < 4; ++pp) {
      float sx, sy;
      if ((pp >> 1) == 0) {
        sx = (pp & 1) ? ofv0.z : ofv0.x;
        sy = (pp & 1) ? ofv0.w : ofv0.y;
      } else {
        sx = (pp & 1) ? ofv1.z : ofv1.x;
        sy = (pp & 1) ? ofv1.w : ofv1.y;
      }
      float ox = __shfl(sx, src, 64);
      float oy = __shfl(sy, src, 64);
      float sa = pp == 0 ? atv.x : pp == 1 ? atv.y : pp == 2 ? atv.z : atv.w;
      float aw = __shfl(sa, src, 64);

      float xx = fx + ox;
      float yy = fy + oy;
      float x0f = floorf(xx), y0f = floorf(yy);
      float wx = xx - x0f, wy = yy - y0f;
      int x0 = (int)x0f, y0 = (int)y0f;
      float w00 = (1.f - wx) * (1.f - wy) * aw;
      float w01 = wx * (1.f - wy) * aw;
      float w10 = (1.f - wx) * wy * aw;
      float w11 = wx * wy * aw;
      auto corner = [&](int xi, int yi, float wgt) {
        bool valid = (xi >= 0) && (xi < Wl) && (yi >= 0) && (yi < Hl);
        int xc = xi < 0 ? 0 : (xi > Wl - 1 ? Wl - 1 : xi);
        int yc = yi < 0 ? 0 : (yi > Hl - 1 ? Hl - 1 : yi);
        short8 d = *(const short8*)(vb + (((size_t)(yc * Wl + xc)) << 8));
        float wg = valid ? wgt : 0.f;
#pragma unroll
        for (int i = 0; i < 8; ++i) acc[i] = fmaf(wg, bf2f((ushort)d[i]), acc[i]);
      };
      corner(x0, y0, w00);
      corner(x0 + 1, y0, w01);
      corner(x0, y0 + 1, w10);
      corner(x0 + 1, y0 + 1, w11);
    }
  }
  ushort o[8];
#pragma unroll
  for (int i = 0; i < 8; ++i) o[i] = f2bf(acc[i]);
  *(short8*)(samp + (bn << 8) + (lh << 3)) =
      (short8){(short)o[0], (short)o[1], (short)o[2], (short)o[3],
               (short)o[4], (short)o[5], (short)o[6], (short)o[7]};
}

// ---------------- final head: (B*N,256)@(256,7)+b, one wave per row ---------
__global__ void head_kernel(const float* __restrict__ hid, const float* __restrict__ W2,
                            const float* __restrict__ b2, float* __restrict__ outp) {
  int gid = blockIdx.x * 256 + threadIdx.x;
  int wave = gid >> 6;
  int lane = threadIdx.x & 63;
  if (wave >= kB * kN) return;
  const float* hrow = hid + ((size_t)wave << 8);
  float acc[kNCLS];
#pragma unroll
  for (int j = 0; j < kNCLS; ++j) acc[j] = 0.f;
  for (int k = lane; k < kC; k += 64) {
    float hv = hrow[k];
    const float* wr = W2 + k * kNCLS;
#pragma unroll
    for (int j = 0; j < kNCLS; ++j) acc[j] = fmaf(hv, wr[j], acc[j]);
  }
#pragma unroll
  for (int m = 32; m > 0; m >>= 1) {
#pragma unroll
    for (int j = 0; j < kNCLS; ++j) acc[j] += __shfl_xor(acc[j], m);
  }
  float r = 0.f;
#pragma unroll
  for (int j = 0; j < kNCLS; ++j)
    if (lane == j) r = acc[j] + b2[j];
  if (lane < kNCLS) outp[(size_t)wave * kNCLS + lane] = r;
}

}  // namespace

extern "C" void kernel_launch(void* const* d_in, const int* in_sizes, int n_in,
                              void* d_out, int out_size, void* d_ws, size_t ws_size,
                              hipStream_t stream) {
  const float* q_t    = (const float*)d_in[0];
  const float* h_t    = (const float*)d_in[1];
  const float* p_head = (const float*)d_in[2];
  const float* W_off  = (const float*)d_in[3];
  const float* b_off  = (const float*)d_in[4];
  const float* W_attn = (const float*)d_in[5];
  const float* b_attn = (const float*)d_in[6];
  const float* W_v    = (const float*)d_in[7];
  const float* b_v    = (const float*)d_in[8];
  const float* W_o    = (const float*)d_in[9];
  const float* b_o    = (const float*)d_in[10];
  const float* W_p1   = (const float*)d_in[11];
  const float* b_p1   = (const float*)d_in[12];
  const float* W_p2   = (const float*)d_in[13];
  const float* b_p2   = (const float*)d_in[14];
  float* out = (float*)d_out;
  char* wsb = (char*)d_ws;

  ushort* value = (ushort*)(wsb + 55705600);     // 55,705,600 (6800-stride)
  ushort* q_bf  = (ushort*)(wsb + 111411200);    //  8,388,608
  float*  offb  = (float*)(wsb + 119799808);     // 16,777,216
  float*  attnl = (float*)(wsb + 136577024);     //  8,388,608 (raw logits)
  ushort* samp  = (ushort*)(wsb + 144965632);    //  8,388,608
  float*  hid   = (float*)(wsb + 161742848);     // 16,777,216
  ushort* wtp   = (ushort*)(wsb + 178520064);
  ushort* Wt_v   = wtp;                 // [256][256]
  ushort* Wt_oa  = wtp + 65536;         // [384][256]
  ushort* Wt_p1  = wtp + 229376;        // [256][512]
  ushort* Wt_p1c = wtp + 360448;        // [256][512] combined
  float*  bp1c   = (float*)(wtp + 491520);  // [256] fp32

  cast_f2b_kernel<<<4096, 256, 0, stream>>>(q_t, q_bf, kB * kN * 64);

  wtrans_all_kernel<<<dim3(8, 16, 4), 256, 0, stream>>>(
      W_v, W_off, W_attn, W_p1,
      Wt_v, Wt_oa, Wt_oa + 65536, Wt_p1);

  // fold W_o into W_p1 bottom half (kills the q_local GEMM)
  wcomb_kernel<<<256, 256, 0, stream>>>(W_o, W_p1, b_o, b_p1, Wt_p1, Wt_p1c, bp1c);

  // value_L0 = h_t @ W_v + b_v  (M64xN128 form, frozen)
  gemm_f32a_kernel<<<dim3(2, 1280), 256, 0, stream>>>(h_t, Wt_v, b_v, value);

  // value pyramid: one fused kernel, in-register cascade per 8x8 patch
  pool_all_kernel<<<1280, 256, 0, stream>>>(value);

  gemm_bf16_kernel<256, false, 2, false><<<dim3(3, 128), 256, 0, stream>>>(
      q_bf, nullptr, Wt_oa, b_off, b_attn, offb, attnl, 256);

  // deformable sampling (batch-owning XCD swizzle for per-XCD L2 residency)
  deform_kernel<<<2048, 256, 0, stream>>>(value, offb, attnl, p_head, samp);

  // hid = relu(q_t@Wp1t + samp@Wc + b')  (split-K, q_local GEMM eliminated)
  gemm_bf16_kernel<512, true, 0, true><<<dim3(2, 128), 256, 0, stream>>>(
      q_bf, samp, Wt_p1c, bp1c, nullptr, hid, nullptr, 256);

  head_kernel<<<4096, 256, 0, stream>>>(hid, W_p2, b_p2, out);
}

// Round 18
// 138.265 us; speedup vs baseline: 1.0487x; 1.0486x over previous
//
#include <hip/hip_runtime.h>
#include <math.h>

// ---------------------------------------------------------------------------
// B=16, N=1024, C=256, SIZE=(512,640), STRIDE=8 -> H0=64, W0=80, P_TOK=5120
// NHEAD=8, NLVL=4, NPTS=4, HD=32, NUM_CLASSES=7
// pyramid: (64,80)(32,40)(16,20)(8,10); S_total=6800
// Identities: pool2x2 linear => pyramid built AFTER projection; W_o folded
//   into W_p1 bottom half (q_local GEMM eliminated).
// r18: gemm_f32a = M64 x FULL-N256 per block (2 panels share one staged A).
//   Mechanism: kernel is L3->L2 fill-BW bound (~2.7 TB/s invariant across
//   r11/r13/r15/r16; warm replays show 0.7 TB/s HBM = A is L3-resident).
//   Full-N halves A fetch 164->84 MB. Scheduling/occupancy proven non-binding.
// ---------------------------------------------------------------------------

namespace {

constexpr int kB = 16;
constexpr int kN = 1024;
constexpr int kC = 256;
constexpr int kNCLS = 7;
constexpr int kSTOT = 6800;

typedef __attribute__((ext_vector_type(8))) short short8;
typedef __attribute__((ext_vector_type(4))) float f32x4;

__device__ inline ushort f2bf(float f) {
  union { float f; unsigned u; } v; v.f = f;
  unsigned r = (v.u + 0x7fffu + ((v.u >> 16) & 1u)) >> 16;
  return (ushort)r;
}
__device__ inline float bf2f(ushort h) {
  union { unsigned u; float f; } v; v.u = ((unsigned)h) << 16;
  return v.f;
}

__device__ inline void gload16(const ushort* g, ushort* l) {
  __builtin_amdgcn_global_load_lds(
      (const __attribute__((address_space(1))) void*)g,
      (__attribute__((address_space(3))) void*)l, 16, 0, 0);
}

// ---------------- q_t cast ---------------------------------------------------
__global__ void cast_f2b_kernel(const float* __restrict__ in, ushort* __restrict__ out, int n4) {
  int i = blockIdx.x * 256 + threadIdx.x;
  if (i >= n4) return;
  float4 v = ((const float4*)in)[i];
  ((ushort4*)out)[i] = make_ushort4(f2bf(v.x), f2bf(v.y), f2bf(v.z), f2bf(v.w));
}

// ---------------- fused pyramid: one 8x8 L0 patch -> L1+L2+L3 ---------------
__global__ void pool_all_kernel(ushort* __restrict__ val) {
  int blk = blockIdx.x;  // 1280 = 16*8*10
  int X = blk % 10;
  int t2 = blk / 10;
  int Y = t2 % 8;
  int b = t2 / 8;
  int c = threadIdx.x;
  const ushort* base = val + (((size_t)b * kSTOT + (Y * 8) * 80 + X * 8) << 8) + c;

  float l1[16];
#pragma unroll
  for (int i = 0; i < 16; ++i) {
    int iy = i >> 2, ix = i & 3;
    const ushort* p = base + (((iy * 2) * 80 + ix * 2) << 8);
    l1[i] = 0.25f * (bf2f(p[0]) + bf2f(p[256]) + bf2f(p[80 * 256]) + bf2f(p[80 * 256 + 256]));
  }
#pragma unroll
  for (int i = 0; i < 16; ++i) {
    int iy = i >> 2, ix = i & 3;
    val[(((size_t)b * kSTOT + 5120 + (Y * 4 + iy) * 40 + X * 4 + ix) << 8) + c] = f2bf(l1[i]);
  }
  float l2[4];
#pragma unroll
  for (int j = 0; j < 4; ++j) {
    int jy = j >> 1, jx = j & 1;
    l2[j] = 0.25f * (l1[(2 * jy) * 4 + 2 * jx] + l1[(2 * jy) * 4 + 2 * jx + 1] +
                     l1[(2 * jy + 1) * 4 + 2 * jx] + l1[(2 * jy + 1) * 4 + 2 * jx + 1]);
    val[(((size_t)b * kSTOT + 6400 + (Y * 2 + jy) * 20 + X * 2 + jx) << 8) + c] = f2bf(l2[j]);
  }
  float l3 = 0.25f * (l2[0] + l2[1] + l2[2] + l2[3]);
  val[(((size_t)b * kSTOT + 6720 + Y * 10 + X) << 8) + c] = f2bf(l3);
}

// ---------------- weight transposes (W_o dropped — folded away) -------------
__global__ void wtrans_all_kernel(const float* __restrict__ s0, const float* __restrict__ s1,
                                  const float* __restrict__ s2, const float* __restrict__ s3,
                                  ushort* __restrict__ d0, ushort* __restrict__ d1,
                                  ushort* __restrict__ d2, ushort* __restrict__ d3) {
  __shared__ float t[32][33];
  const float* W; ushort* Wt; int K, N;
  switch (blockIdx.z) {
    case 0: W = s0; Wt = d0; K = 256; N = 256; break;
    case 1: W = s1; Wt = d1; K = 256; N = 256; break;
    case 2: W = s2; Wt = d2; K = 256; N = 128; break;
    default: W = s3; Wt = d3; K = 512; N = 256; break;
  }
  int nx = blockIdx.x << 5, ky = blockIdx.y << 5;
  if (nx >= N || ky >= K) return;
  int lx = threadIdx.x & 31, ly = threadIdx.x >> 5;
#pragma unroll
  for (int i = 0; i < 32; i += 8)
    t[ly + i][lx] = W[(size_t)(ky + ly + i) * N + nx + lx];
  __syncthreads();
#pragma unroll
  for (int i = 0; i < 32; i += 8)
    Wt[(size_t)(nx + ly + i) * K + ky + lx] = f2bf(t[lx][ly + i]);
}

// ---------------- weight fold: Wt_p1c = [Wp1t^T | (W_o@Wp1b)^T], bias' ------
__global__ void wcomb_kernel(const float* __restrict__ W_o, const float* __restrict__ W_p1,
                             const float* __restrict__ b_o, const float* __restrict__ b_p1,
                             const ushort* __restrict__ Wt_p1,
                             ushort* __restrict__ Wt_p1c, float* __restrict__ bp1c) {
  __shared__ float wcol[256];
  __shared__ float wsum[4];
  int h = blockIdx.x;
  int in = threadIdx.x;
  wcol[in] = W_p1[(size_t)(256 + in) * 256 + h];
  __syncthreads();
  float s = 0.f;
  const float* wo = W_o + (size_t)in * 256;
#pragma unroll 4
  for (int out = 0; out < 256; ++out) s = fmaf(wo[out], wcol[out], s);
  Wt_p1c[(size_t)h * 512 + 256 + in] = f2bf(s);
  Wt_p1c[(size_t)h * 512 + in] = Wt_p1[(size_t)h * 512 + in];
  float part = b_o[in] * wcol[in];
#pragma unroll
  for (int m = 32; m > 0; m >>= 1) part += __shfl_xor(part, m);
  if ((in & 63) == 0) wsum[in >> 6] = part;
  __syncthreads();
  if (in == 0) bp1c[h] = b_p1[h] + wsum[0] + wsum[1] + wsum[2] + wsum[3];
}

// ---------------- bf16 MFMA GEMM, 128x128 tile (small-M GEMMs) --------------
template <int KTOT, bool SPLITK, int OMODE, bool RELU>
__global__ __launch_bounds__(256) void gemm_bf16_kernel(
    const ushort* __restrict__ A, const ushort* __restrict__ A2,
    const ushort* __restrict__ Wt, const float* __restrict__ bias,
    const float* __restrict__ bias2, void* __restrict__ Cout,
    void* __restrict__ Cout2, int ldc) {
  __shared__ ushort Asm[2][128 * 32];
  __shared__ ushort Bsm[2][128 * 32];
  const int tid = threadIdx.x;
  const int w = tid >> 6, l = tid & 63;
  const int bm = blockIdx.y << 7, bn = blockIdx.x << 7;
  const int wm = w >> 1, wn = w & 1;

  const int c0 = w * 2, c1 = w * 2 + 1;
  const int G0 = c0 * 64 + l, G1 = c1 * 64 + l;
  const int r0 = G0 >> 2, g0 = G0 & 3;
  const int r1 = G1 >> 2, g1 = G1 & 3;
  const int sz0 = (g0 ^ ((r0 >> 1) & 3)) << 3;
  const int sz1 = (g1 ^ ((r1 >> 1) & 3)) << 3;
  const int ak = SPLITK ? 256 : KTOT;
  const ushort* sA0 = A + (size_t)(bm + r0) * ak + sz0;
  const ushort* sA1 = A + (size_t)(bm + r1) * ak + sz1;
  const ushort* sA0b = SPLITK ? A2 + (size_t)(bm + r0) * 256 + sz0 : nullptr;
  const ushort* sA1b = SPLITK ? A2 + (size_t)(bm + r1) * 256 + sz1 : nullptr;
  const ushort* sB0 = Wt + (size_t)(bn + r0) * KTOT + sz0;
  const ushort* sB1 = Wt + (size_t)(bn + r1) * KTOT + sz1;

  const int e = l >> 4, rl = l & 15;
  int aoff[4], boff[4];
#pragma unroll
  for (int i = 0; i < 4; ++i) {
    int r = wm * 64 + i * 16 + rl;
    aoff[i] = r * 32 + ((e ^ ((r >> 1) & 3)) << 3);
    int rb = wn * 64 + i * 16 + rl;
    boff[i] = rb * 32 + ((e ^ ((rb >> 1) & 3)) << 3);
  }

  f32x4 acc[4][4];
#pragma unroll
  for (int i = 0; i < 4; ++i)
#pragma unroll
    for (int j = 0; j < 4; ++j) acc[i][j] = (f32x4){0.f, 0.f, 0.f, 0.f};

  auto stage = [&](int buf, int k0) {
    const ushort *a0, *a1;
    if (SPLITK && k0 >= 256) {
      a0 = sA0b + (k0 - 256);
      a1 = sA1b + (k0 - 256);
    } else {
      a0 = sA0 + k0;
      a1 = sA1 + k0;
    }
    gload16(a0, &Asm[buf][c0 * 512]);
    gload16(a1, &Asm[buf][c1 * 512]);
    gload16(sB0 + k0, &Bsm[buf][c0 * 512]);
    gload16(sB1 + k0, &Bsm[buf][c1 * 512]);
  };

  constexpr int nt = KTOT / 32;
  stage(0, 0);
  __syncthreads();
  for (int t = 0; t < nt; ++t) {
    const int cur = t & 1;
    if (t + 1 < nt) stage(cur ^ 1, (t + 1) * 32);
    short8 af[4], bfr[4];
#pragma unroll
    for (int i = 0; i < 4; ++i) af[i] = *(const short8*)&Asm[cur][aoff[i]];
#pragma unroll
    for (int j = 0; j < 4; ++j) bfr[j] = *(const short8*)&Bsm[cur][boff[j]];
#pragma unroll
    for (int i = 0; i < 4; ++i)
#pragma unroll
      for (int j = 0; j < 4; ++j)
        acc[i][j] = __builtin_amdgcn_mfma_f32_16x16x32_bf16(bfr[j], af[i], acc[i][j], 0, 0, 0);
    __syncthreads();
  }

  // epilogue (swapped layout): reg r = channel ch+r, lane&15 = spatial row
#pragma unroll
  for (int j = 0; j < 4; ++j) {
    int ch = bn + wn * 64 + j * 16 + e * 4;
    float4 b4;
    if (OMODE == 2)
      b4 = (ch < 256) ? *(const float4*)(bias + ch) : *(const float4*)(bias2 + ch - 256);
    else
      b4 = *(const float4*)(bias + ch);
    float bv[4] = {b4.x, b4.y, b4.z, b4.w};
#pragma unroll
    for (int i = 0; i < 4; ++i) {
      int sp = bm + wm * 64 + i * 16 + rl;
      float v[4];
#pragma unroll
      for (int r = 0; r < 4; ++r) {
        v[r] = acc[i][j][r] + bv[r];
        if (RELU) v[r] = fmaxf(v[r], 0.f);
      }
      if (OMODE == 0) {
        *(float4*)&((float*)Cout)[(size_t)sp * ldc + ch] = make_float4(v[0], v[1], v[2], v[3]);
      } else if (OMODE == 1) {
        *(ushort4*)&((ushort*)Cout)[(size_t)sp * ldc + ch] =
            make_ushort4(f2bf(v[0]), f2bf(v[1]), f2bf(v[2]), f2bf(v[3]));
      } else {
        if (ch < 256)
          *(float4*)&((float*)Cout)[(size_t)sp * 256 + ch] = make_float4(v[0], v[1], v[2], v[3]);
        else
          *(float4*)&((float*)Cout2)[(size_t)sp * 128 + (ch - 256)] =
              make_float4(v[0], v[1], v[2], v[3]);
      }
    }
  }
}

// ---------------- fp32-A GEMM: value_L0 = h_t @ W_v + b_v -------------------
// M64 x FULL-N256 per block: A staged ONCE per K-step, reused by both 128-col
// B panels -> A L3 fetch halves (164 -> 84 MB). The kernel is L3->L2 fill-BW
// bound (~2.7 TB/s invariant across r11/r13/r15/r16 scheduling variants).
// LDS 40KB (A 2x4KB dbuf + B 2x16KB dbuf). Panel MFMAs sequenced to keep
// B-fragment live range small.
__global__ __launch_bounds__(256) void gemm_f32a_kernel(
    const float* __restrict__ A, const ushort* __restrict__ Wt,
    const float* __restrict__ bias, ushort* __restrict__ Cout) {
  __shared__ ushort Asm[2][64 * 32];    // 4 KB each
  __shared__ ushort Bsm[2][256 * 32];   // 16 KB each
  const int tid = threadIdx.x;
  const int w = tid >> 6, l = tid & 63;
  const int by = blockIdx.x;            // 1280 M-tiles of 64 rows
  const int bm = by << 6;
  const int wm = w >> 1, wn = w & 1;    // wave: rows wm*32.., cols wn*64 (per panel)

  // A staging: thread -> row ar = tid>>2, k-octet aq = tid&3 (8 floats)
  const int ar = tid >> 2, aq = tid & 3;
  const float* aSrc = A + (size_t)(bm + ar) * 256 + aq * 8;
  const int adst = ar * 32 + ((aq ^ ((ar >> 1) & 3)) << 3);

  // B staging: 16 chunks of 1KB (256 rows x 32 cols bf16); wave w -> 4w..4w+3
  const ushort* sB[4];
#pragma unroll
  for (int k = 0; k < 4; ++k) {
    int G = (w * 4 + k) * 64 + l, r = G >> 2, g = G & 3;
    sB[k] = Wt + (size_t)r * 256 + ((g ^ ((r >> 1) & 3)) << 3);
  }

  const int e = l >> 4, rl = l & 15;
  int aoff[2], boff0[4], boff1[4];
#pragma unroll
  for (int i = 0; i < 2; ++i) {
    int r = wm * 32 + i * 16 + rl;
    aoff[i] = r * 32 + ((e ^ ((r >> 1) & 3)) << 3);
  }
#pragma unroll
  for (int j = 0; j < 4; ++j) {
    int rb0 = wn * 64 + j * 16 + rl;          // panel 0 rows 0..127
    boff0[j] = rb0 * 32 + ((e ^ ((rb0 >> 1) & 3)) << 3);
    int rb1 = 128 + wn * 64 + j * 16 + rl;    // panel 1 rows 128..255
    boff1[j] = rb1 * 32 + ((e ^ ((rb1 >> 1) & 3)) << 3);
  }

  f32x4 acc0[2][4], acc1[2][4];
#pragma unroll
  for (int i = 0; i < 2; ++i)
#pragma unroll
    for (int j = 0; j < 4; ++j) {
      acc0[i][j] = (f32x4){0.f, 0.f, 0.f, 0.f};
      acc1[i][j] = (f32x4){0.f, 0.f, 0.f, 0.f};
    }

  float4 av0, av1;
  auto loadA = [&](int k0) {
    av0 = *(const float4*)(aSrc + k0);
    av1 = *(const float4*)(aSrc + k0 + 4);
  };
  auto writeA = [&](int buf) {
    *(short8*)&Asm[buf][adst] =
        (short8){(short)f2bf(av0.x), (short)f2bf(av0.y), (short)f2bf(av0.z), (short)f2bf(av0.w),
                 (short)f2bf(av1.x), (short)f2bf(av1.y), (short)f2bf(av1.z), (short)f2bf(av1.w)};
  };
  auto stageB = [&](int buf, int k0) {
#pragma unroll
    for (int k = 0; k < 4; ++k) gload16(sB[k] + k0, &Bsm[buf][(w * 4 + k) * 512]);
  };

  loadA(0);
  stageB(0, 0);
  writeA(0);
  __syncthreads();
  for (int t = 0; t < 8; ++t) {
    const int cur = t & 1;
    if (t < 7) {
      loadA((t + 1) * 32);   // issue next A loads early (hide under MFMA)
      stageB(cur ^ 1, (t + 1) * 32);
    }
    short8 af[2];
#pragma unroll
    for (int i = 0; i < 2; ++i) af[i] = *(const short8*)&Asm[cur][aoff[i]];
    {
      short8 b0[4];
#pragma unroll
      for (int j = 0; j < 4; ++j) b0[j] = *(const short8*)&Bsm[cur][boff0[j]];
#pragma unroll
      for (int i = 0; i < 2; ++i)
#pragma unroll
        for (int j = 0; j < 4; ++j)
          acc0[i][j] = __builtin_amdgcn_mfma_f32_16x16x32_bf16(b0[j], af[i], acc0[i][j], 0, 0, 0);
    }
    {
      short8 b1[4];
#pragma unroll
      for (int j = 0; j < 4; ++j) b1[j] = *(const short8*)&Bsm[cur][boff1[j]];
#pragma unroll
      for (int i = 0; i < 2; ++i)
#pragma unroll
        for (int j = 0; j < 4; ++j)
          acc1[i][j] = __builtin_amdgcn_mfma_f32_16x16x32_bf16(b1[j], af[i], acc1[i][j], 0, 0, 0);
    }
    if (t < 7) writeA(cur ^ 1);
    __syncthreads();
  }

  // epilogue (swapped layout) into value's 6800-stride L0 region
  const int b = by / 80;
  const int sb = (by - b * 80) << 6;
  ushort* outB = Cout + (((size_t)(b * 6800 + sb)) << 8);
#pragma unroll
  for (int j = 0; j < 4; ++j) {
    int ch0 = wn * 64 + j * 16 + e * 4;
    int ch1 = 128 + ch0;
    float4 b40 = *(const float4*)(bias + ch0);
    float4 b41 = *(const float4*)(bias + ch1);
    float bv0[4] = {b40.x, b40.y, b40.z, b40.w};
    float bv1[4] = {b41.x, b41.y, b41.z, b41.w};
#pragma unroll
    for (int i = 0; i < 2; ++i) {
      int sp = wm * 32 + i * 16 + rl;
      float v0[4], v1[4];
#pragma unroll
      for (int r = 0; r < 4; ++r) {
        v0[r] = acc0[i][j][r] + bv0[r];
        v1[r] = acc1[i][j][r] + bv1[r];
      }
      *(ushort4*)&outB[(size_t)sp * 256 + ch0] =
          make_ushort4(f2bf(v0[0]), f2bf(v0[1]), f2bf(v0[2]), f2bf(v0[3]));
      *(ushort4*)&outB[(size_t)sp * 256 + ch1] =
          make_ushort4(f2bf(v1[0]), f2bf(v1[1]), f2bf(v1[2]), f2bf(v1[3]));
    }
  }
}

// ---------------- deformable sampling, softmax fused ------------------------
// Batch-owning XCD swizzle (r17, neutral but harmless — kept).
__global__ void deform_kernel(
    const ushort* __restrict__ value, const float* __restrict__ off,
    const float* __restrict__ attnl, const float* __restrict__ p_head,
    ushort* __restrict__ samp) {
  int blk = (int)blockIdx.x;            // 2048 blocks
  int xcd = blk & 7;
  int j = blk >> 3;
  int wvi = (xcd << 10) + (j << 2) + (threadIdx.x >> 6);
  int l = threadIdx.x & 63;
  int nq = l >> 5;
  int lh = l & 31;
  int h = lh >> 2;
  int pt = wvi * 2 + nq;
  int b = pt >> 10;
  size_t bn = (size_t)pt;

  float ph = (lh < 2) ? p_head[bn * 2 + lh] : 0.f;
  float px = __shfl(ph, (nq << 5) + 0, 64) * (1.0f / 640.0f);
  float py = __shfl(ph, (nq << 5) + 1, 64) * (1.0f / 512.0f);
  px = fminf(fmaxf(px, 0.f), 1.f);
  py = fminf(fmaxf(py, 0.f), 1.f);

  const float4* offp = (const float4*)(off + (bn << 8));
  float4 ofv0 = offp[2 * lh];
  float4 ofv1 = offp[2 * lh + 1];
  float4 atv = ((const float4*)(attnl + (bn << 7)))[lh];

  float m = fmaxf(fmaxf(atv.x, atv.y), fmaxf(atv.z, atv.w));
  m = fmaxf(m, __shfl_xor(m, 1, 64));
  m = fmaxf(m, __shfl_xor(m, 2, 64));
  float e0 = expf(atv.x - m), e1 = expf(atv.y - m);
  float e2 = expf(atv.z - m), e3 = expf(atv.w - m);
  float s = e0 + e1 + e2 + e3;
  s += __shfl_xor(s, 1, 64);
  s += __shfl_xor(s, 2, 64);
  float inv = 1.f / s;
  atv = make_float4(e0 * inv, e1 * inv, e2 * inv, e3 * inv);

  float acc[8];
#pragma unroll
  for (int i = 0; i < 8; ++i) acc[i] = 0.f;
  const ushort* vbb = value + (((size_t)b * kSTOT) << 8) + (lh << 3);

#pragma unroll 1
  for (int lv = 0; lv < 4; ++lv) {
    const int Wl = 80 >> lv, Hl = 64 >> lv;
    const int offL = (lv == 0) ? 0 : (lv == 1) ? 5120 : (lv == 2) ? 6400 : 6720;
    const ushort* vb = vbb + (((size_t)offL) << 8);
    const int src = (nq << 5) + (h << 2) + lv;
    const float fx = px * (float)Wl - 0.5f;
    const float fy = py * (float)Hl - 0.5f;
#pragma unroll
    for (int pp = 0; pp < 4; ++pp) {
      float sx, sy;
      if ((pp >> 1) == 0) {
        sx = (pp & 1) ? ofv0.z : ofv0.x;
        sy = (pp & 1) ? ofv0.w : ofv0.y;
      } else {
        sx = (pp & 1) ? ofv1.z : ofv1.x;
        sy = (pp & 1) ? ofv1.w : ofv1.y;
      }
      float ox = __shfl(sx, src, 64);
      float oy = __shfl(sy, src, 64);
      float sa = pp == 0 ? atv.x : pp == 1 ? atv.y : pp == 2 ? atv.z : atv.w;
      float aw = __shfl(sa, src, 64);

      float xx = fx + ox;
      float yy = fy + oy;
      float x0f = floorf(xx), y0f = floorf(yy);
      float wx = xx - x0f, wy = yy - y0f;
      int x0 = (int)x0f, y0 = (int)y0f;
      float w00 = (1.f - wx) * (1.f - wy) * aw;
      float w01 = wx * (1.f - wy) * aw;
      float w10 = (1.f - wx) * wy * aw;
      float w11 = wx * wy * aw;
      auto corner = [&](int xi, int yi, float wgt) {
        bool valid = (xi >= 0) && (xi < Wl) && (yi >= 0) && (yi < Hl);
        int xc = xi < 0 ? 0 : (xi > Wl - 1 ? Wl - 1 : xi);
        int yc = yi < 0 ? 0 : (yi > Hl - 1 ? Hl - 1 : yi);
        short8 d = *(const short8*)(vb + (((size_t)(yc * Wl + xc)) << 8));
        float wg = valid ? wgt : 0.f;
#pragma unroll
        for (int i = 0; i < 8; ++i) acc[i] = fmaf(wg, bf2f((ushort)d[i]), acc[i]);
      };
      corner(x0, y0, w00);
      corner(x0 + 1, y0, w01);
      corner(x0, y0 + 1, w10);
      corner(x0 + 1, y0 + 1, w11);
    }
  }
  ushort o[8];
#pragma unroll
  for (int i = 0; i < 8; ++i) o[i] = f2bf(acc[i]);
  *(short8*)(samp + (bn << 8) + (lh << 3)) =
      (short8){(short)o[0], (short)o[1], (short)o[2], (short)o[3],
               (short)o[4], (short)o[5], (short)o[6], (short)o[7]};
}

// ---------------- final head: (B*N,256)@(256,7)+b, one wave per row ---------
__global__ void head_kernel(const float* __restrict__ hid, const float* __restrict__ W2,
                            const float* __restrict__ b2, float* __restrict__ outp) {
  int gid = blockIdx.x * 256 + threadIdx.x;
  int wave = gid >> 6;
  int lane = threadIdx.x & 63;
  if (wave >= kB * kN) return;
  const float* hrow = hid + ((size_t)wave << 8);
  float acc[kNCLS];
#pragma unroll
  for (int j = 0; j < kNCLS; ++j) acc[j] = 0.f;
  for (int k = lane; k < kC; k += 64) {
    float hv = hrow[k];
    const float* wr = W2 + k * kNCLS;
#pragma unroll
    for (int j = 0; j < kNCLS; ++j) acc[j] = fmaf(hv, wr[j], acc[j]);
  }
#pragma unroll
  for (int m = 32; m > 0; m >>= 1) {
#pragma unroll
    for (int j = 0; j < kNCLS; ++j) acc[j] += __shfl_xor(acc[j], m);
  }
  float r = 0.f;
#pragma unroll
  for (int j = 0; j < kNCLS; ++j)
    if (lane == j) r = acc[j] + b2[j];
  if (lane < kNCLS) outp[(size_t)wave * kNCLS + lane] = r;
}

}  // namespace

extern "C" void kernel_launch(void* const* d_in, const int* in_sizes, int n_in,
                              void* d_out, int out_size, void* d_ws, size_t ws_size,
                              hipStream_t stream) {
  const float* q_t    = (const float*)d_in[0];
  const float* h_t    = (const float*)d_in[1];
  const float* p_head = (const float*)d_in[2];
  const float* W_off  = (const float*)d_in[3];
  const float* b_off  = (const float*)d_in[4];
  const float* W_attn = (const float*)d_in[5];
  const float* b_attn = (const float*)d_in[6];
  const float* W_v    = (const float*)d_in[7];
  const float* b_v    = (const float*)d_in[8];
  const float* W_o    = (const float*)d_in[9];
  const float* b_o    = (const float*)d_in[10];
  const float* W_p1   = (const float*)d_in[11];
  const float* b_p1   = (const float*)d_in[12];
  const float* W_p2   = (const float*)d_in[13];
  const float* b_p2   = (const float*)d_in[14];
  float* out = (float*)d_out;
  char* wsb = (char*)d_ws;

  ushort* value = (ushort*)(wsb + 55705600);     // 55,705,600 (6800-stride)
  ushort* q_bf  = (ushort*)(wsb + 111411200);    //  8,388,608
  float*  offb  = (float*)(wsb + 119799808);     // 16,777,216
  float*  attnl = (float*)(wsb + 136577024);     //  8,388,608 (raw logits)
  ushort* samp  = (ushort*)(wsb + 144965632);    //  8,388,608
  float*  hid   = (float*)(wsb + 161742848);     // 16,777,216
  ushort* wtp   = (ushort*)(wsb + 178520064);
  ushort* Wt_v   = wtp;                 // [256][256]
  ushort* Wt_oa  = wtp + 65536;         // [384][256]
  ushort* Wt_p1  = wtp + 229376;        // [256][512]
  ushort* Wt_p1c = wtp + 360448;        // [256][512] combined
  float*  bp1c   = (float*)(wtp + 491520);  // [256] fp32

  cast_f2b_kernel<<<4096, 256, 0, stream>>>(q_t, q_bf, kB * kN * 64);

  wtrans_all_kernel<<<dim3(8, 16, 4), 256, 0, stream>>>(
      W_v, W_off, W_attn, W_p1,
      Wt_v, Wt_oa, Wt_oa + 65536, Wt_p1);

  // fold W_o into W_p1 bottom half (kills the q_local GEMM)
  wcomb_kernel<<<256, 256, 0, stream>>>(W_o, W_p1, b_o, b_p1, Wt_p1, Wt_p1c, bp1c);

  // value_L0 = h_t @ W_v + b_v  (M64 x full-N256: A staged once, fetch halved)
  gemm_f32a_kernel<<<1280, 256, 0, stream>>>(h_t, Wt_v, b_v, value);

  // value pyramid: one fused kernel, in-register cascade per 8x8 patch
  pool_all_kernel<<<1280, 256, 0, stream>>>(value);

  gemm_bf16_kernel<256, false, 2, false><<<dim3(3, 128), 256, 0, stream>>>(
      q_bf, nullptr, Wt_oa, b_off, b_attn, offb, attnl, 256);

  // deformable sampling (batch-owning XCD swizzle)
  deform_kernel<<<2048, 256, 0, stream>>>(value, offb, attnl, p_head, samp);

  // hid = relu(q_t@Wp1t + samp@Wc + b')  (split-K, q_local GEMM eliminated)
  gemm_bf16_kernel<512, true, 0, true><<<dim3(2, 128), 256, 0, stream>>>(
      q_bf, samp, Wt_p1c, bp1c, nullptr, hid, nullptr, 256);

  head_kernel<<<4096, 256, 0, stream>>>(hid, W_p2, b_p2, out);
}